// Round 1
// baseline (1057.694 us; speedup 1.0000x reference)
//
#include <hip/hip_runtime.h>

#define SEQ 512
#define BATCH 4096
#define IND 64
#define HID 128
#define MROWS 16

typedef __attribute__((ext_vector_type(4))) float f32x4;
typedef __attribute__((ext_vector_type(8))) __bf16 bf16x8;
typedef __attribute__((ext_vector_type(4))) __bf16 bf16x4;

__device__ __forceinline__ float tanh_fast(float x) {
    x = fminf(10.f, fmaxf(-10.f, x));
    float e = __expf(2.f * x);
    return __fdividef(e - 1.f, e + 1.f);
}

// One block = 16 batch rows, persistent across all 512 timesteps.
// 4 waves; wave w computes output columns [w*32, w*32+32).
// K = 192 = [x_t (64) | h_{t-1} (128)], mfma_f32_16x16x32_bf16, fp32 accum.
// Weights live in VGPRs (12 B-frags/wave); h and x double-buffered in LDS.
__global__ __launch_bounds__(256, 1) void rnn_kernel(
    const float* __restrict__ x, const float* __restrict__ Wih,
    const float* __restrict__ bih, const float* __restrict__ Whh,
    const float* __restrict__ bhh, float* __restrict__ out)
{
    // +8 bf16 row pad (16B) keeps ds_read_b128 16B-aligned and breaks
    // the 16-way bank conflict (stride%32dw==4 -> 2-way, free).
    __shared__ __align__(16) __bf16 xs[2][MROWS][72];
    __shared__ __align__(16) __bf16 hs[2][MROWS][136];

    const int tid  = threadIdx.x;
    const int wave = tid >> 6, lane = tid & 63;
    const int quad = lane >> 4, m16 = lane & 15;
    const int nbase = wave * 32;
    const int b0 = blockIdx.x * MROWS;

    // ---- Preload B fragments (combined W^T) into registers ----
    // B[k][n]: n = lane&15 (within 16-col tile), k = quad*8 + j
    bf16x8 bfrag[2][6];
    #pragma unroll
    for (int tile = 0; tile < 2; ++tile) {
        #pragma unroll
        for (int kc = 0; kc < 6; ++kc) {
            const int n  = nbase + tile * 16 + m16;
            const int k0 = kc * 32 + quad * 8;
            const float* src = (k0 < IND) ? (Wih + n * IND + k0)
                                          : (Whh + n * HID + (k0 - IND));
            bf16x8 b;
            #pragma unroll
            for (int j = 0; j < 8; ++j) b[j] = (__bf16)src[j];
            bfrag[tile][kc] = b;
        }
    }

    const int n0 = nbase + m16;                 // abs col of tile 0 (C: col=lane&15)
    const float bias0 = bih[n0] + bhh[n0];
    const float bias1 = bih[n0 + 16] + bhh[n0 + 16];

    // ---- h_0 = 0 ----
    {
        unsigned* hz = (unsigned*)&hs[0][0][0];
        for (int i = tid; i < MROWS * 136 / 2; i += 256) hz[i] = 0u;
    }

    // ---- x staging: each thread owns one float4 of the 16x64 tile ----
    const int xr = tid >> 4;            // row 0..15
    const int xc = (tid & 15) * 4;      // col 0..60
    const float* xg = x + (size_t)(b0 + xr) * IND + xc;
    const size_t xstep = (size_t)BATCH * IND;

    f32x4 v0     = *(const f32x4*)(xg);          // x_0
    f32x4 pf_cur = *(const f32x4*)(xg + xstep);  // x_1
    {
        bf16x4 w;
        w[0] = (__bf16)v0[0]; w[1] = (__bf16)v0[1];
        w[2] = (__bf16)v0[2]; w[3] = (__bf16)v0[3];
        *(bf16x4*)&xs[0][xr][xc] = w;
    }
    __syncthreads();

    for (int t = 0; t < SEQ; ++t) {
        const int buf = t & 1;

        // issue prefetch of x_{t+2} (stays in flight across the barrier:
        // raw s_barrier below does NOT drain vmcnt)
        f32x4 pf_nxt;
        if (t + 2 < SEQ) pf_nxt = *(const f32x4*)(xg + (size_t)(t + 2) * xstep);

        // ---- A fragments: A[m=lane&15][k=quad*8+j] ----
        bf16x8 af[6];
        const __bf16* xp = &xs[buf][0][0] + m16 * 72  + quad * 8;
        const __bf16* hp = &hs[buf][0][0] + m16 * 136 + quad * 8;
        #pragma unroll
        for (int kc = 0; kc < 2; ++kc) af[kc]     = *(const bf16x8*)(xp + kc * 32);
        #pragma unroll
        for (int kc = 0; kc < 4; ++kc) af[2 + kc] = *(const bf16x8*)(hp + kc * 32);

        f32x4 acc0 = {0.f, 0.f, 0.f, 0.f};
        f32x4 acc1 = {0.f, 0.f, 0.f, 0.f};
        #pragma unroll
        for (int kc = 0; kc < 6; ++kc) {
            acc0 = __builtin_amdgcn_mfma_f32_16x16x32_bf16(af[kc], bfrag[0][kc], acc0, 0, 0, 0);
            acc1 = __builtin_amdgcn_mfma_f32_16x16x32_bf16(af[kc], bfrag[1][kc], acc1, 0, 0, 0);
        }

        // ---- stage x_{t+1} into the other buffer ----
        if (t + 1 < SEQ) {
            bf16x4 w;
            w[0] = (__bf16)pf_cur[0]; w[1] = (__bf16)pf_cur[1];
            w[2] = (__bf16)pf_cur[2]; w[3] = (__bf16)pf_cur[3];
            *(bf16x4*)&xs[buf ^ 1][xr][xc] = w;
        }

        // ---- epilogue: bias + tanh; C layout col=lane&15, row=quad*4+r ----
        if (t == SEQ - 1) {
            #pragma unroll
            for (int r = 0; r < 4; ++r) {
                const int row = quad * 4 + r;
                out[(size_t)(b0 + row) * HID + n0]      = tanh_fast(acc0[r] + bias0);
                out[(size_t)(b0 + row) * HID + n0 + 16] = tanh_fast(acc1[r] + bias1);
            }
        } else {
            __bf16* hw = &hs[buf ^ 1][0][0];
            #pragma unroll
            for (int r = 0; r < 4; ++r) {
                const int row = quad * 4 + r;
                hw[row * 136 + n0]      = (__bf16)tanh_fast(acc0[r] + bias0);
                hw[row * 136 + n0 + 16] = (__bf16)tanh_fast(acc1[r] + bias1);
            }
        }

        if (t + 2 < SEQ) pf_cur = pf_nxt;

        // LDS-only barrier: drain DS ops, leave the global prefetch in flight.
        __asm__ __volatile__("s_waitcnt lgkmcnt(0)\n\ts_barrier" ::: "memory");
    }
}

extern "C" void kernel_launch(void* const* d_in, const int* in_sizes, int n_in,
                              void* d_out, int out_size, void* d_ws, size_t ws_size,
                              hipStream_t stream) {
    const float* x   = (const float*)d_in[0];
    const float* Wih = (const float*)d_in[1];
    const float* bih = (const float*)d_in[2];
    const float* Whh = (const float*)d_in[3];
    const float* bhh = (const float*)d_in[4];
    float* out = (float*)d_out;

    dim3 grid(BATCH / MROWS);   // 256 blocks, 16 batch rows each
    dim3 block(256);            // 4 waves
    hipLaunchKernelGGL(rnn_kernel, grid, block, 0, stream, x, Wih, bih, Whh, bhh, out);
}